// Round 1
// baseline (261.036 us; speedup 1.0000x reference)
//
#include <hip/hip_runtime.h>

#define SIG 2.8853900817779268f   // 2 * log2(e)

__device__ __forceinline__ float rcp_f (float x){ return __builtin_amdgcn_rcpf(x);  }
__device__ __forceinline__ float exp2_f(float x){ return __builtin_amdgcn_exp2f(x); }
__device__ __forceinline__ float log2_f(float x){ return __builtin_amdgcn_logf(x);  }

// Block: 448 threads = 7 waves; wave s handles permutation s for 64 consecutive m.
__global__ __launch_bounds__(448) void maron_kernel(
    const float* __restrict__ x,      // (64,14,1024)
    const float* __restrict__ W1,     // (14,16)
    const float* __restrict__ b1,     // (16)
    const float* __restrict__ W2,     // (16,1)
    const float* __restrict__ b2p,    // (1)
    const float* __restrict__ fW1,    // (120,16)
    const float* __restrict__ fb1,    // (16)
    const float* __restrict__ fW2,    // (16,1)
    const float* __restrict__ fb2p,   // (1)
    float* __restrict__ out,          // (M) out ++ (M) L
    int M)
{
    __shared__ float red[7][64][17];  // stride 17 (odd) -> conflict-free

    const int tid = threadIdx.x;
    const int s   = tid >> 6;         // 0..6  (wave-uniform)
    const int ml  = tid & 63;
    const int m   = blockIdx.x * 64 + ml;
    const int bb  = m >> 10;
    const int tt  = m & 1023;

    const float* xb = x + (size_t)bb * 14 * 1024 + tt;

    // permuted active columns: slot0 -> col i0, slot1 -> col i1 (first group),
    // slot7 -> 7+i0, slot8 -> 7+i1
    const int i0 = (7 - s) % 7;
    const int i1 = (8 - s) % 7;

    const float lu = fmaxf(log2_f(xb[(i0    ) * 1024]), -40.f);
    const float lv = fmaxf(log2_f(xb[(i1    ) * 1024]), -40.f);
    const float lw = fmaxf(log2_f(xb[(7 + i0) * 1024]), -40.f);
    const float lz = fmaxf(log2_f(xb[(7 + i1) * 1024]), -40.f);

    // Bias including the 10 always-one slots, pre-scaled by SIG for the tanh-exp trick
    float Bs[16];
#pragma unroll
    for (int k = 0; k < 16; ++k) {
        float v = b1[k];
        v += W1[2*16+k] + W1[3*16+k] + W1[4*16+k] + W1[5*16+k] + W1[6*16+k];
        v += W1[9*16+k] + W1[10*16+k] + W1[11*16+k] + W1[12*16+k] + W1[13*16+k];
        Bs[k] = SIG * v;
    }
    float C2 = b2p[0];
#pragma unroll
    for (int k = 0; k < 16; ++k) C2 += W2[k];

    float acc[16];
#pragma unroll
    for (int k = 0; k < 16; ++k) acc[k] = 0.f;
    float Lsum = 0.f;

    int r = 0;
    float fa = 0.f;
    for (int a = 0; a <= 7; ++a, fa += 1.f) {
        const float pa  = exp2_f(fa * lu);   // a==0 -> 1 even when lu == -40
        const float spa = SIG * pa;
        float A_[16];
#pragma unroll
        for (int k = 0; k < 16; ++k) A_[k] = fmaf(spa, W1[0*16+k], Bs[k]);

        float fb = 0.f;
        for (int bi = 0; bi <= 7 - a; ++bi, fb += 1.f) {
            const float pb  = exp2_f(fb * lv);
            const float spb = SIG * pb;
            const float pab = pa * pb;
            float AB_[16];
#pragma unroll
            for (int k = 0; k < 16; ++k) AB_[k] = fmaf(spb, W1[1*16+k], A_[k]);

            float fc = 0.f;
            float fd = (float)(7 - a - bi);
            for (int ci = 0; ci <= 7 - a - bi; ++ci, fc += 1.f, fd -= 1.f, ++r) {
                const float pc  = exp2_f(fc * lw);
                const float spc = SIG * pc;
                const float pd  = exp2_f(fd * lz);
                const float spd = SIG * pd;
                const float mul = pab * (pc * pd);

                float s2 = 0.f;
#pragma unroll
                for (int k = 0; k < 16; ++k) {
                    const float tk = fmaf(spd, W1[8*16+k], fmaf(spc, W1[7*16+k], AB_[k]));
                    const float rk = rcp_f(exp2_f(tk) + 1.0f);
                    s2 = fmaf(W2[k], rk, s2);
                }
                const float mulnn = fmaf(-2.f, s2, C2);   // b2 + sum W2*tanh
                Lsum += fabsf(mul - mulnn);

                const float* frow = fW1 + (r << 4);       // wave-uniform row
#pragma unroll
                for (int k = 0; k < 16; ++k) acc[k] = fmaf(mulnn, frow[k], acc[k]);
            }
        }
    }

    // reduce the 7 permutations
#pragma unroll
    for (int k = 0; k < 16; ++k) red[s][ml][k] = acc[k];
    red[s][ml][16] = Lsum;
    __syncthreads();

    if (tid < 64) {
        float aq[16];
#pragma unroll
        for (int k = 0; k < 16; ++k) aq[k] = red[0][ml][k];
        float Lt = red[0][ml][16];
#pragma unroll
        for (int ss = 1; ss < 7; ++ss) {
#pragma unroll
            for (int k = 0; k < 16; ++k) aq[k] += red[ss][ml][k];
            Lt += red[ss][ml][16];
        }

        float o = fb2p[0];
        float s3 = 0.f;
#pragma unroll
        for (int k = 0; k < 16; ++k) {
            const float a2 = SIG * (aq[k] + fb1[k]);
            const float rk = rcp_f(exp2_f(a2) + 1.f);
            s3 = fmaf(fW2[k], rk, s3);
            o += fW2[k];
        }
        o = fmaf(-2.f, s3, o);

        out[m]     = o;
        out[M + m] = Lt * (1.f / 120.f);
    }
}

extern "C" void kernel_launch(void* const* d_in, const int* in_sizes, int n_in,
                              void* d_out, int out_size, void* d_ws, size_t ws_size,
                              hipStream_t stream) {
    const float* x   = (const float*)d_in[0];
    const float* W1  = (const float*)d_in[1];
    const float* b1  = (const float*)d_in[2];
    const float* W2  = (const float*)d_in[3];
    const float* b2  = (const float*)d_in[4];
    const float* fW1 = (const float*)d_in[5];
    const float* fb1 = (const float*)d_in[6];
    const float* fW2 = (const float*)d_in[7];
    const float* fb2 = (const float*)d_in[8];

    const int M = out_size / 2;           // 65536
    const int blocks = M / 64;            // 1024

    maron_kernel<<<blocks, 448, 0, stream>>>(x, W1, b1, W2, b2, fW1, fb1, fW2, fb2,
                                             (float*)d_out, M);
}